// Round 7
// baseline (893.202 us; speedup 1.0000x reference)
//
#include <hip/hip_runtime.h>
#include <cstdint>
#include <cstddef>

#define NFEAT 500
#define NHID  128
#define NCLASS 40

typedef __attribute__((ext_vector_type(8))) short bf16x8;
typedef __attribute__((ext_vector_type(4))) float f32x4;

__device__ __forceinline__ unsigned short f2bf(float f) {
    union { float f; unsigned u; } v; v.f = f;
    unsigned u = v.u;
    unsigned r = u + 0x7FFF + ((u >> 16) & 1);   // round-to-nearest-even
    return (unsigned short)(r >> 16);
}
__device__ __forceinline__ float bf2f(unsigned short h) {
    union { unsigned u; float f; } v; v.u = ((unsigned)h) << 16; return v.f;
}

// ---------------- CSR construction ----------------

__global__ void k_hist(const int* __restrict__ row, int E, int* __restrict__ counts) {
    int i = blockIdx.x * 256 + threadIdx.x;
    if (i < E) atomicAdd(&counts[row[i]], 1);
}

__global__ void k_block_sum(const int* __restrict__ counts, int n, int* __restrict__ partials) {
    __shared__ int tmp[256];
    int i = blockIdx.x * 256 + threadIdx.x;
    tmp[threadIdx.x] = (i < n) ? counts[i] : 0;
    __syncthreads();
    for (int o = 128; o > 0; o >>= 1) {
        if (threadIdx.x < o) tmp[threadIdx.x] += tmp[threadIdx.x + o];
        __syncthreads();
    }
    if (threadIdx.x == 0) partials[blockIdx.x] = tmp[0];
}

__global__ void k_scan_partials(int* __restrict__ partials, int nb) {
    __shared__ int tmp[512];
    int t = threadIdx.x;
    int v = (t < nb) ? partials[t] : 0;
    tmp[t] = v;
    __syncthreads();
    for (int o = 1; o < 512; o <<= 1) {
        int add = (t >= o) ? tmp[t - o] : 0;
        __syncthreads();
        tmp[t] += add;
        __syncthreads();
    }
    if (t < nb) partials[t] = tmp[t] - v;   // exclusive
}

// also zeroes counts for reuse as cursor
__global__ void k_scan_counts(int* __restrict__ counts, const int* __restrict__ partials,
                              int* __restrict__ row_ptr, int n) {
    __shared__ int tmp[256];
    int t = threadIdx.x;
    int i = blockIdx.x * 256 + t;
    int v = (i < n) ? counts[i] : 0;
    tmp[t] = v;
    __syncthreads();
    for (int o = 1; o < 256; o <<= 1) {
        int add = (t >= o) ? tmp[t - o] : 0;
        __syncthreads();
        tmp[t] += add;
        __syncthreads();
    }
    int incl = tmp[t];
    int base = partials[blockIdx.x];
    if (i < n) {
        row_ptr[i] = base + incl - v;
        counts[i] = 0;
    }
    if (i == n - 1) row_ptr[n] = base + incl;
}

__global__ void k_scatter(const int* __restrict__ row, const int* __restrict__ col,
                          const float* __restrict__ w, int E,
                          const int* __restrict__ row_ptr, int* __restrict__ cursor,
                          uint2* __restrict__ csr_cw) {
    int i = blockIdx.x * 256 + threadIdx.x;
    if (i < E) {
        int r = row[i];
        int p = row_ptr[r] + atomicAdd(&cursor[r], 1);
        csr_cw[p] = make_uint2((unsigned)col[i], __float_as_uint(w[i]));
    }
}

// ---------------- weight prep: W[K][N] fp32 -> Wt[Nt][Kpad] bf16 (transposed, zero-padded) ----------------

__global__ void k_prep_w(const float* __restrict__ W, unsigned short* __restrict__ Wt,
                         int K, int Norig, int Nt, int Kpad) {
    int idx = blockIdx.x * 256 + threadIdx.x;
    if (idx >= Nt * Kpad) return;
    int n = idx / Kpad, k = idx % Kpad;
    unsigned short v = 0;
    if (k < K && n < Norig) v = f2bf(W[(size_t)k * Norig + n]);
    Wt[idx] = v;
}

// ---------------- direct-register MFMA GEMM (no LDS, no barriers) ----------------
// C[M][CPITCH] = A[M][K] @ Wt^T. 256 threads = 4 independent waves; each wave owns 32
// distinct rows (TM=2) x BN cols (TN=BN/16) -> zero inter-wave A reuse, so A-fragments
// load DIRECTLY global->register (16 contiguous B per lane; wave = 16 rows x 64 B
// fully-used segments). B-fragments direct from L1/L2-hot Wt. Both register
// double-buffered: step k+1 loads issue before step k uses -> vmcnt(N) keeps them in
// flight; no __syncthreads anywhere -> every wave streams independently.
// fp32 A (layer 1): raw float4s staged, converted to bf16 just before MFMA.

template<bool AFP32, int KPAD, int BN, int CN, int CPITCH>
__global__ __launch_bounds__(256) void k_gemm_direct(const void* __restrict__ Ain,
                                                     const unsigned short* __restrict__ Wt,
                                                     unsigned short* __restrict__ C,
                                                     int M, int K) {
    constexpr int TM = 2;
    constexpr int TN = BN / 16;
    constexpr int NIT = KPAD / 32;
    const int t = threadIdx.x;
    const int lane = t & 63;
    const int w = t >> 6;
    const int l15 = lane & 15, quad = lane >> 4;
    const int rbase = blockIdx.x * 128 + w * 32;

    const float* Af = (const float*)Ain;
    const unsigned short* Ab = (const unsigned short*)Ain;

    f32x4 acc[TM][TN];
#pragma unroll
    for (int mi = 0; mi < TM; mi++)
#pragma unroll
        for (int ni = 0; ni < TN; ni++)
            acc[mi][ni] = (f32x4){0.f, 0.f, 0.f, 0.f};

    int rowi[TM];
#pragma unroll
    for (int mi = 0; mi < TM; mi++) {
        int r = rbase + mi * 16 + l15;
        rowi[mi] = AFP32 ? min(r, M - 1) : r;   // bf16 buffers are Mpad-padded
    }

    float4 fA[2][TM][2];   // fp32 staging [set][mi][half]
    bf16x8 hA[2][TM];      // bf16 staging
    bf16x8 hB[2][TN];

    auto loadA = [&](int set, int k0) {
        if (AFP32) {
            int gk = k0 + quad * 8;
#pragma unroll
            for (int mi = 0; mi < TM; mi++) {
                const float* p = Af + (size_t)rowi[mi] * K + gk;
                fA[set][mi][0] = (gk + 4 <= K) ? *(const float4*)p : make_float4(0.f, 0.f, 0.f, 0.f);
                fA[set][mi][1] = (gk + 8 <= K) ? *(const float4*)(p + 4) : make_float4(0.f, 0.f, 0.f, 0.f);
            }
        } else {
#pragma unroll
            for (int mi = 0; mi < TM; mi++)
                hA[set][mi] = *(const bf16x8*)(Ab + (size_t)rowi[mi] * KPAD + k0 + quad * 8);
        }
    };
    auto loadB = [&](int set, int k0) {
#pragma unroll
        for (int ni = 0; ni < TN; ni++)
            hB[set][ni] = *(const bf16x8*)(Wt + (size_t)(ni * 16 + l15) * KPAD + k0 + quad * 8);
    };
    auto compute = [&](int set) {
        bf16x8 afr[TM];
#pragma unroll
        for (int mi = 0; mi < TM; mi++) {
            if (AFP32) {
                float4 u = fA[set][mi][0], v = fA[set][mi][1];
                bf16x8 r;
                r[0] = (short)f2bf(u.x); r[1] = (short)f2bf(u.y);
                r[2] = (short)f2bf(u.z); r[3] = (short)f2bf(u.w);
                r[4] = (short)f2bf(v.x); r[5] = (short)f2bf(v.y);
                r[6] = (short)f2bf(v.z); r[7] = (short)f2bf(v.w);
                afr[mi] = r;
            } else {
                afr[mi] = hA[set][mi];
            }
        }
#pragma unroll
        for (int mi = 0; mi < TM; mi++)
#pragma unroll
            for (int ni = 0; ni < TN; ni++)
                acc[mi][ni] = __builtin_amdgcn_mfma_f32_16x16x32_bf16(afr[mi], hB[set][ni], acc[mi][ni], 0, 0, 0);
    };

    loadA(0, 0);
    loadB(0, 0);
    for (int it = 0; it < NIT; it += 2) {
        if (it + 1 < NIT) { loadA(1, (it + 1) * 32); loadB(1, (it + 1) * 32); }
        compute(0);
        if (it + 2 < NIT) { loadA(0, (it + 2) * 32); loadB(0, (it + 2) * 32); }
        if (it + 1 < NIT) compute(1);
    }

    // epilogue: C/D layout col=lane&15, row=quad*4+reg ; rows Mpad-padded -> no M guard
#pragma unroll
    for (int mi = 0; mi < TM; mi++) {
#pragma unroll
        for (int r = 0; r < 4; r++) {
            int gm = rbase + mi * 16 + quad * 4 + r;
#pragma unroll
            for (int ni = 0; ni < TN; ni++) {
                int gn = ni * 16 + l15;
                if (gn < CN) C[(size_t)gm * CPITCH + gn] = f2bf(acc[mi][ni][r]);
            }
        }
    }
}

// ---------------- SpMM (width 128, bf16) + bias + optional ReLU ----------------

__global__ __launch_bounds__(256) void k_spmm128(const unsigned short* __restrict__ S,
                                                 const int* __restrict__ rp,
                                                 const uint2* __restrict__ cw,
                                                 const float* __restrict__ bias,
                                                 unsigned short* __restrict__ out,
                                                 int n, int do_relu) {
    int wid  = threadIdx.x >> 6;
    int lane = threadIdx.x & 63;
    int node = blockIdx.x * 4 + wid;
    if (node >= n) return;
    int s = rp[node], e = rp[node + 1];
    float a0x = 0.f, a0y = 0.f, a1x = 0.f, a1y = 0.f;
    float a2x = 0.f, a2y = 0.f, a3x = 0.f, a3y = 0.f;
    int i = s;
    for (; i + 4 <= e; i += 4) {
        uint2 e0 = cw[i], e1 = cw[i + 1], e2 = cw[i + 2], e3 = cw[i + 3];
        unsigned v0 = ((const unsigned*)(S + (size_t)e0.x * NHID))[lane];
        unsigned v1 = ((const unsigned*)(S + (size_t)e1.x * NHID))[lane];
        unsigned v2 = ((const unsigned*)(S + (size_t)e2.x * NHID))[lane];
        unsigned v3 = ((const unsigned*)(S + (size_t)e3.x * NHID))[lane];
        float w0 = __uint_as_float(e0.y), w1 = __uint_as_float(e1.y);
        float w2 = __uint_as_float(e2.y), w3 = __uint_as_float(e3.y);
        a0x = fmaf(w0, bf2f((unsigned short)v0), a0x); a0y = fmaf(w0, bf2f((unsigned short)(v0 >> 16)), a0y);
        a1x = fmaf(w1, bf2f((unsigned short)v1), a1x); a1y = fmaf(w1, bf2f((unsigned short)(v1 >> 16)), a1y);
        a2x = fmaf(w2, bf2f((unsigned short)v2), a2x); a2y = fmaf(w2, bf2f((unsigned short)(v2 >> 16)), a2y);
        a3x = fmaf(w3, bf2f((unsigned short)v3), a3x); a3y = fmaf(w3, bf2f((unsigned short)(v3 >> 16)), a3y);
    }
    for (; i < e; i++) {
        uint2 e0 = cw[i];
        unsigned v0 = ((const unsigned*)(S + (size_t)e0.x * NHID))[lane];
        float w0 = __uint_as_float(e0.y);
        a0x = fmaf(w0, bf2f((unsigned short)v0), a0x); a0y = fmaf(w0, bf2f((unsigned short)(v0 >> 16)), a0y);
    }
    float ax = (a0x + a1x) + (a2x + a3x) + bias[lane * 2];
    float ay = (a0y + a1y) + (a2y + a3y) + bias[lane * 2 + 1];
    if (do_relu) {
        ax = fmaxf(ax, 0.f);
        ay = fmaxf(ay, 0.f);
    }
    unsigned o = (unsigned)f2bf(ax) | ((unsigned)f2bf(ay) << 16);
    __builtin_nontemporal_store(o, (unsigned*)(out + (size_t)node * NHID) + lane);
}

// ---------------- SpMM (width 40, bf16 pitch 40) + bias + log_softmax -> fp32 out ----------------

__global__ __launch_bounds__(256) void k_spmm40_lsm(const unsigned short* __restrict__ S,
                                                    const int* __restrict__ rp,
                                                    const uint2* __restrict__ cw,
                                                    const float* __restrict__ bias,
                                                    float* __restrict__ out,
                                                    int n) {
    int wid  = threadIdx.x >> 6;
    int lane = threadIdx.x & 63;
    int node = blockIdx.x * 4 + wid;
    if (node >= n) return;
    int s = rp[node], e = rp[node + 1];
    float a0 = 0.f, a1 = 0.f, a2 = 0.f, a3 = 0.f;
    int i = s;
    bool act = lane < NCLASS;
    for (; i + 4 <= e; i += 4) {
        uint2 e0 = cw[i], e1 = cw[i + 1], e2 = cw[i + 2], e3 = cw[i + 3];
        if (act) {
            float v0 = bf2f(S[(size_t)e0.x * NCLASS + lane]);
            float v1 = bf2f(S[(size_t)e1.x * NCLASS + lane]);
            float v2 = bf2f(S[(size_t)e2.x * NCLASS + lane]);
            float v3 = bf2f(S[(size_t)e3.x * NCLASS + lane]);
            a0 = fmaf(__uint_as_float(e0.y), v0, a0);
            a1 = fmaf(__uint_as_float(e1.y), v1, a1);
            a2 = fmaf(__uint_as_float(e2.y), v2, a2);
            a3 = fmaf(__uint_as_float(e3.y), v3, a3);
        }
    }
    for (; i < e; i++) {
        uint2 e0 = cw[i];
        if (act) a0 = fmaf(__uint_as_float(e0.y), bf2f(S[(size_t)e0.x * NCLASS + lane]), a0);
    }
    float acc = (a0 + a1) + (a2 + a3);
    float logit = act ? acc + bias[lane] : -INFINITY;
    float m = logit;
#pragma unroll
    for (int o = 32; o >= 1; o >>= 1) m = fmaxf(m, __shfl_xor(m, o, 64));
    float ex = act ? expf(logit - m) : 0.f;
    float ssum = ex;
#pragma unroll
    for (int o = 32; o >= 1; o >>= 1) ssum += __shfl_xor(ssum, o, 64);
    if (act) {
        float r = logit - m - logf(ssum);
        __builtin_nontemporal_store(r, out + (size_t)node * NCLASS + lane);
    }
}

// ---------------- launch ----------------

extern "C" void kernel_launch(void* const* d_in, const int* in_sizes, int n_in,
                              void* d_out, int out_size, void* d_ws, size_t ws_size,
                              hipStream_t stream) {
    const float* x  = (const float*)d_in[0];
    const int* row  = (const int*)d_in[1];
    const int* col  = (const int*)d_in[2];
    const float* ew = (const float*)d_in[3];
    const float* W1 = (const float*)d_in[4];
    const float* b1 = (const float*)d_in[5];
    const float* W2 = (const float*)d_in[6];
    const float* b2 = (const float*)d_in[7];
    const float* W3 = (const float*)d_in[8];
    const float* b3 = (const float*)d_in[9];
    const float* W4 = (const float*)d_in[10];
    const float* b4 = (const float*)d_in[11];
    float* out = (float*)d_out;

    const int Nn = in_sizes[0] / NFEAT;
    const int E  = in_sizes[1];
    const int NB = (Nn + 255) / 256;
    const int Mpad = (Nn + 127) & ~127;

    char* ws = (char*)d_ws;
    size_t off = 0;
    auto alloc = [&](size_t bytes) {
        size_t o = off;
        off = (off + bytes + 255) & ~(size_t)255;
        return o;
    };
    int*   row_ptr  = (int*)(ws + alloc((size_t)(Nn + 1) * 4));
    int*   counts   = (int*)(ws + alloc((size_t)Nn * 4));       // also reused as cursor
    int*   partials = (int*)(ws + alloc((size_t)NB * 4));
    uint2* csr_cw   = (uint2*)(ws + alloc((size_t)E * 8));
    unsigned short* Sb  = (unsigned short*)(ws + alloc((size_t)Mpad * NHID * 2));
    unsigned short* Hb  = (unsigned short*)(ws + alloc((size_t)Mpad * NHID * 2));
    unsigned short* S4b = (unsigned short*)(ws + alloc((size_t)Mpad * NCLASS * 2));
    unsigned short* Wt1 = (unsigned short*)(ws + alloc((size_t)128 * 512 * 2));
    unsigned short* Wt2 = (unsigned short*)(ws + alloc((size_t)128 * 128 * 2));
    unsigned short* Wt3 = (unsigned short*)(ws + alloc((size_t)128 * 128 * 2));
    unsigned short* Wt4 = (unsigned short*)(ws + alloc((size_t)48 * 128 * 2));

    // ---- weight prep ----
    k_prep_w<<<(128 * 512 + 255) / 256, 256, 0, stream>>>(W1, Wt1, NFEAT, NHID, 128, 512);
    k_prep_w<<<(128 * 128 + 255) / 256, 256, 0, stream>>>(W2, Wt2, NHID, NHID, 128, 128);
    k_prep_w<<<(128 * 128 + 255) / 256, 256, 0, stream>>>(W3, Wt3, NHID, NHID, 128, 128);
    k_prep_w<<<(48 * 128 + 255) / 256, 256, 0, stream>>>(W4, Wt4, NHID, NCLASS, 48, 128);

    // ---- CSR build ----
    (void)hipMemsetAsync(counts, 0, (size_t)Nn * 4, stream);
    k_hist<<<(E + 255) / 256, 256, 0, stream>>>(row, E, counts);
    k_block_sum<<<NB, 256, 0, stream>>>(counts, Nn, partials);
    k_scan_partials<<<1, 512, 0, stream>>>(partials, NB);
    k_scan_counts<<<NB, 256, 0, stream>>>(counts, partials, row_ptr, Nn);
    k_scatter<<<(E + 255) / 256, 256, 0, stream>>>(row, col, ew, E, row_ptr, counts, csr_cw);

    const int gblocks = Mpad / 128;
    const int spmm_blocks = (Nn + 3) / 4;

    // layer 1: x @ W1 -> Sb ; spmm+b1+relu -> Hb
    k_gemm_direct<true, 512, 128, 128, 128><<<gblocks, 256, 0, stream>>>(x, Wt1, Sb, Nn, NFEAT);
    k_spmm128<<<spmm_blocks, 256, 0, stream>>>(Sb, row_ptr, csr_cw, b1, Hb, Nn, 1);
    // layer 2
    k_gemm_direct<false, 128, 128, 128, 128><<<gblocks, 256, 0, stream>>>(Hb, Wt2, Sb, Nn, NHID);
    k_spmm128<<<spmm_blocks, 256, 0, stream>>>(Sb, row_ptr, csr_cw, b2, Hb, Nn, 1);
    // layer 3
    k_gemm_direct<false, 128, 128, 128, 128><<<gblocks, 256, 0, stream>>>(Hb, Wt3, Sb, Nn, NHID);
    k_spmm128<<<spmm_blocks, 256, 0, stream>>>(Sb, row_ptr, csr_cw, b3, Hb, Nn, 1);
    // layer 4: Hb @ W4 -> S4b[N,40] ; spmm+b4+log_softmax -> out (fp32)
    k_gemm_direct<false, 128, 48, 40, 40><<<gblocks, 256, 0, stream>>>(Hb, Wt4, S4b, Nn, NHID);
    k_spmm40_lsm<<<spmm_blocks, 256, 0, stream>>>(S4b, row_ptr, csr_cw, b4, out, Nn);
}

// Round 8
// 879.624 us; speedup vs baseline: 1.0154x; 1.0154x over previous
//
#include <hip/hip_runtime.h>
#include <cstdint>
#include <cstddef>

#define NFEAT 500
#define NHID  128
#define NCLASS 40

typedef __attribute__((ext_vector_type(8))) short bf16x8;
typedef __attribute__((ext_vector_type(4))) float f32x4;

__device__ __forceinline__ unsigned short f2bf(float f) {
    union { float f; unsigned u; } v; v.f = f;
    unsigned u = v.u;
    unsigned r = u + 0x7FFF + ((u >> 16) & 1);   // round-to-nearest-even
    return (unsigned short)(r >> 16);
}
__device__ __forceinline__ float bf2f(unsigned short h) {
    union { unsigned u; float f; } v; v.u = ((unsigned)h) << 16; return v.f;
}

// ---------------- CSR construction ----------------

__global__ void k_hist(const int* __restrict__ row, int E, int* __restrict__ counts) {
    int i = blockIdx.x * 256 + threadIdx.x;
    if (i < E) atomicAdd(&counts[row[i]], 1);
}

__global__ void k_block_sum(const int* __restrict__ counts, int n, int* __restrict__ partials) {
    __shared__ int tmp[256];
    int i = blockIdx.x * 256 + threadIdx.x;
    tmp[threadIdx.x] = (i < n) ? counts[i] : 0;
    __syncthreads();
    for (int o = 128; o > 0; o >>= 1) {
        if (threadIdx.x < o) tmp[threadIdx.x] += tmp[threadIdx.x + o];
        __syncthreads();
    }
    if (threadIdx.x == 0) partials[blockIdx.x] = tmp[0];
}

__global__ void k_scan_partials(int* __restrict__ partials, int nb) {
    __shared__ int tmp[512];
    int t = threadIdx.x;
    int v = (t < nb) ? partials[t] : 0;
    tmp[t] = v;
    __syncthreads();
    for (int o = 1; o < 512; o <<= 1) {
        int add = (t >= o) ? tmp[t - o] : 0;
        __syncthreads();
        tmp[t] += add;
        __syncthreads();
    }
    if (t < nb) partials[t] = tmp[t] - v;   // exclusive
}

// also zeroes counts for reuse as cursor
__global__ void k_scan_counts(int* __restrict__ counts, const int* __restrict__ partials,
                              int* __restrict__ row_ptr, int n) {
    __shared__ int tmp[256];
    int t = threadIdx.x;
    int i = blockIdx.x * 256 + t;
    int v = (i < n) ? counts[i] : 0;
    tmp[t] = v;
    __syncthreads();
    for (int o = 1; o < 256; o <<= 1) {
        int add = (t >= o) ? tmp[t - o] : 0;
        __syncthreads();
        tmp[t] += add;
        __syncthreads();
    }
    int incl = tmp[t];
    int base = partials[blockIdx.x];
    if (i < n) {
        row_ptr[i] = base + incl - v;
        counts[i] = 0;
    }
    if (i == n - 1) row_ptr[n] = base + incl;
}

__global__ void k_scatter(const int* __restrict__ row, const int* __restrict__ col,
                          const float* __restrict__ w, int E,
                          const int* __restrict__ row_ptr, int* __restrict__ cursor,
                          uint2* __restrict__ csr_cw) {
    int i = blockIdx.x * 256 + threadIdx.x;
    if (i < E) {
        int r = row[i];
        int p = row_ptr[r] + atomicAdd(&cursor[r], 1);
        csr_cw[p] = make_uint2((unsigned)col[i], __float_as_uint(w[i]));
    }
}

// ---------------- weight prep: W[K][N] fp32 -> Wt[Nt][Kpad] bf16 (transposed, zero-padded) ----------------

__global__ void k_prep_w(const float* __restrict__ W, unsigned short* __restrict__ Wt,
                         int K, int Norig, int Nt, int Kpad) {
    int idx = blockIdx.x * 256 + threadIdx.x;
    if (idx >= Nt * Kpad) return;
    int n = idx / Kpad, k = idx % Kpad;
    unsigned short v = 0;
    if (k < K && n < Norig) v = f2bf(W[(size_t)k * Norig + n]);
    Wt[idx] = v;
}

// ---------------- MFMA GEMM with global_load_lds staging ----------------
// C[M][CPITCH] = A[M][K] @ Wt^T. BM=128, BK=32, 256 threads = 4 waves, each wave owns
// 32 rows x BN cols (TM=2, TN=BN/16). A staged via __builtin_amdgcn_global_load_lds
// (width 16) into double-buffered LDS; the vmcnt queue holds the full next tile
// (16 KB fp32 / 8 KB bf16 per block) in flight across the compute phase -> ~48 KB/CU
// outstanding, well past the latency-BW product. LDS layout chunk-column-major:
// chunk(kc,m) at (kc*128+m)*16B (kc = 8-col group for bf16 / 8-float group split in
// two 16B halves for fp32) -- contiguous in stage order, uniform bank spread on reads.
// B fragments: direct global->register from L2-hot Wt, double-buffered, issued BEFORE
// the stage calls so compute's vmcnt wait never drains the A prefetch.
// fp32 (layer 1): clamped addresses for K-tail/M-overrun; garbage hits zero-padded Wt.

template<bool AFP32, int KPAD, int BN, int CN, int CPITCH>
__global__ __launch_bounds__(256) void k_gemm_lds(const void* __restrict__ Ain,
                                                  const unsigned short* __restrict__ Wt,
                                                  unsigned short* __restrict__ C,
                                                  int M, int K) {
    constexpr int TM = 2;
    constexpr int TN = BN / 16;
    constexpr int TB = AFP32 ? 16384 : 8192;   // bytes per tile
    constexpr int NIT = KPAD / 32;
    __shared__ unsigned char As[2][TB];

    const int t = threadIdx.x;
    const int lane = t & 63;
    const int w = t >> 6;
    const int l15 = lane & 15, quad = lane >> 4;
    const int mbase = blockIdx.x * 128;

    const float* Af = (const float*)Ain;
    const unsigned short* Ab = (const unsigned short*)Ain;

    f32x4 acc[TM][TN];
#pragma unroll
    for (int mi = 0; mi < TM; mi++)
#pragma unroll
        for (int ni = 0; ni < TN; ni++)
            acc[mi][ni] = (f32x4){0.f, 0.f, 0.f, 0.f};

    bf16x8 hB[2][TN];
    auto loadB = [&](int s, int k0) {
#pragma unroll
        for (int ni = 0; ni < TN; ni++)
            hB[s][ni] = *(const bf16x8*)(Wt + (size_t)(ni * 16 + l15) * KPAD + k0 + quad * 8);
    };

    auto stage = [&](int b, int k0) {
        unsigned char* lb = &As[b][0];
        if (AFP32) {
            // tile = 128 rows x 32 fp32 cols = 16 KB; 4 passes x 4 KB.
            // linear p*4096 + t*16 == chunk (kc=p, m=t>>1), half=t&1
            int m_ = t >> 1, half = t & 1;
            int grow = mbase + m_; grow = grow < M ? grow : M - 1;
#pragma unroll
            for (int p = 0; p < 4; p++) {
                int col = k0 + p * 8 + half * 4;
                col = (col + 4 <= K) ? col : K - 4;
                const float* g = Af + (size_t)grow * K + col;
                __builtin_amdgcn_global_load_lds(
                    (const __attribute__((address_space(1))) void*)g,
                    (__attribute__((address_space(3))) void*)(lb + p * 4096 + w * 1024 + lane * 16),
                    16, 0, 0);
            }
        } else {
            // tile = 128 rows x 32 bf16 cols = 8 KB; 2 passes x 4 KB.
            // linear p*4096 + t*16 == chunk (kc = p*2 + (t>>7), m = t&127)
            int m_ = t & 127;
            int kcl = t >> 7;
#pragma unroll
            for (int p = 0; p < 2; p++) {
                int kc = p * 2 + kcl;
                const unsigned short* g = Ab + (size_t)(mbase + m_) * KPAD + k0 + kc * 8;
                __builtin_amdgcn_global_load_lds(
                    (const __attribute__((address_space(1))) void*)g,
                    (__attribute__((address_space(3))) void*)(lb + p * 4096 + w * 1024 + lane * 16),
                    16, 0, 0);
            }
        }
    };

    auto compute = [&](int b, int s) {
        const unsigned char* lb = &As[b][0];
        bf16x8 afr[TM];
#pragma unroll
        for (int mi = 0; mi < TM; mi++) {
            int m = w * 32 + mi * 16 + l15;
            if (AFP32) {
                size_t off = ((size_t)quad * 128 + m) * 32;
                float4 u = *(const float4*)(lb + off);
                float4 v = *(const float4*)(lb + off + 16);
                bf16x8 r;
                r[0] = (short)f2bf(u.x); r[1] = (short)f2bf(u.y);
                r[2] = (short)f2bf(u.z); r[3] = (short)f2bf(u.w);
                r[4] = (short)f2bf(v.x); r[5] = (short)f2bf(v.y);
                r[6] = (short)f2bf(v.z); r[7] = (short)f2bf(v.w);
                afr[mi] = r;
            } else {
                size_t off = ((size_t)quad * 128 + m) * 16;
                afr[mi] = *(const bf16x8*)(lb + off);
            }
        }
#pragma unroll
        for (int mi = 0; mi < TM; mi++)
#pragma unroll
            for (int ni = 0; ni < TN; ni++)
                acc[mi][ni] = __builtin_amdgcn_mfma_f32_16x16x32_bf16(afr[mi], hB[s][ni], acc[mi][ni], 0, 0, 0);
    };

    loadB(0, 0);
    stage(0, 0);
    __syncthreads();                      // drains vmcnt: tile 0 + B set 0 ready

    for (int it = 0; it < NIT; it++) {
        const int cur = it & 1;
        const bool more = (it + 1) < NIT;
        if (more) {
            loadB(cur ^ 1, (it + 1) * 32);   // B first: older than A stage in vmcnt order
            stage(cur ^ 1, (it + 1) * 32);   // full next tile into the vmcnt queue
        }
        compute(cur, cur);
        if (more) __syncthreads();           // drains next-tile stage; LDS swap safe
    }

    // epilogue: C/D layout col=lane&15, row=quad*4+reg ; rows Mpad-padded -> no M guard
#pragma unroll
    for (int mi = 0; mi < TM; mi++) {
#pragma unroll
        for (int r = 0; r < 4; r++) {
            int gm = mbase + w * 32 + mi * 16 + quad * 4 + r;
#pragma unroll
            for (int ni = 0; ni < TN; ni++) {
                int gn = ni * 16 + l15;
                if (gn < CN) C[(size_t)gm * CPITCH + gn] = f2bf(acc[mi][ni][r]);
            }
        }
    }
}

// ---------------- SpMM (width 128, bf16) + bias + optional ReLU ----------------

__global__ __launch_bounds__(256) void k_spmm128(const unsigned short* __restrict__ S,
                                                 const int* __restrict__ rp,
                                                 const uint2* __restrict__ cw,
                                                 const float* __restrict__ bias,
                                                 unsigned short* __restrict__ out,
                                                 int n, int do_relu) {
    int wid  = threadIdx.x >> 6;
    int lane = threadIdx.x & 63;
    int node = blockIdx.x * 4 + wid;
    if (node >= n) return;
    int s = rp[node], e = rp[node + 1];
    float a0x = 0.f, a0y = 0.f, a1x = 0.f, a1y = 0.f;
    float a2x = 0.f, a2y = 0.f, a3x = 0.f, a3y = 0.f;
    int i = s;
    for (; i + 4 <= e; i += 4) {
        uint2 e0 = cw[i], e1 = cw[i + 1], e2 = cw[i + 2], e3 = cw[i + 3];
        unsigned v0 = ((const unsigned*)(S + (size_t)e0.x * NHID))[lane];
        unsigned v1 = ((const unsigned*)(S + (size_t)e1.x * NHID))[lane];
        unsigned v2 = ((const unsigned*)(S + (size_t)e2.x * NHID))[lane];
        unsigned v3 = ((const unsigned*)(S + (size_t)e3.x * NHID))[lane];
        float w0 = __uint_as_float(e0.y), w1 = __uint_as_float(e1.y);
        float w2 = __uint_as_float(e2.y), w3 = __uint_as_float(e3.y);
        a0x = fmaf(w0, bf2f((unsigned short)v0), a0x); a0y = fmaf(w0, bf2f((unsigned short)(v0 >> 16)), a0y);
        a1x = fmaf(w1, bf2f((unsigned short)v1), a1x); a1y = fmaf(w1, bf2f((unsigned short)(v1 >> 16)), a1y);
        a2x = fmaf(w2, bf2f((unsigned short)v2), a2x); a2y = fmaf(w2, bf2f((unsigned short)(v2 >> 16)), a2y);
        a3x = fmaf(w3, bf2f((unsigned short)v3), a3x); a3y = fmaf(w3, bf2f((unsigned short)(v3 >> 16)), a3y);
    }
    for (; i < e; i++) {
        uint2 e0 = cw[i];
        unsigned v0 = ((const unsigned*)(S + (size_t)e0.x * NHID))[lane];
        float w0 = __uint_as_float(e0.y);
        a0x = fmaf(w0, bf2f((unsigned short)v0), a0x); a0y = fmaf(w0, bf2f((unsigned short)(v0 >> 16)), a0y);
    }
    float ax = (a0x + a1x) + (a2x + a3x) + bias[lane * 2];
    float ay = (a0y + a1y) + (a2y + a3y) + bias[lane * 2 + 1];
    if (do_relu) {
        ax = fmaxf(ax, 0.f);
        ay = fmaxf(ay, 0.f);
    }
    unsigned o = (unsigned)f2bf(ax) | ((unsigned)f2bf(ay) << 16);
    __builtin_nontemporal_store(o, (unsigned*)(out + (size_t)node * NHID) + lane);
}

// ---------------- SpMM (width 40, bf16 pitch 40) + bias + log_softmax -> fp32 out ----------------

__global__ __launch_bounds__(256) void k_spmm40_lsm(const unsigned short* __restrict__ S,
                                                    const int* __restrict__ rp,
                                                    const uint2* __restrict__ cw,
                                                    const float* __restrict__ bias,
                                                    float* __restrict__ out,
                                                    int n) {
    int wid  = threadIdx.x >> 6;
    int lane = threadIdx.x & 63;
    int node = blockIdx.x * 4 + wid;
    if (node >= n) return;
    int s = rp[node], e = rp[node + 1];
    float a0 = 0.f, a1 = 0.f, a2 = 0.f, a3 = 0.f;
    int i = s;
    bool act = lane < NCLASS;
    for (; i + 4 <= e; i += 4) {
        uint2 e0 = cw[i], e1 = cw[i + 1], e2 = cw[i + 2], e3 = cw[i + 3];
        if (act) {
            float v0 = bf2f(S[(size_t)e0.x * NCLASS + lane]);
            float v1 = bf2f(S[(size_t)e1.x * NCLASS + lane]);
            float v2 = bf2f(S[(size_t)e2.x * NCLASS + lane]);
            float v3 = bf2f(S[(size_t)e3.x * NCLASS + lane]);
            a0 = fmaf(__uint_as_float(e0.y), v0, a0);
            a1 = fmaf(__uint_as_float(e1.y), v1, a1);
            a2 = fmaf(__uint_as_float(e2.y), v2, a2);
            a3 = fmaf(__uint_as_float(e3.y), v3, a3);
        }
    }
    for (; i < e; i++) {
        uint2 e0 = cw[i];
        if (act) a0 = fmaf(__uint_as_float(e0.y), bf2f(S[(size_t)e0.x * NCLASS + lane]), a0);
    }
    float acc = (a0 + a1) + (a2 + a3);
    float logit = act ? acc + bias[lane] : -INFINITY;
    float m = logit;
#pragma unroll
    for (int o = 32; o >= 1; o >>= 1) m = fmaxf(m, __shfl_xor(m, o, 64));
    float ex = act ? expf(logit - m) : 0.f;
    float ssum = ex;
#pragma unroll
    for (int o = 32; o >= 1; o >>= 1) ssum += __shfl_xor(ssum, o, 64);
    if (act) {
        float r = logit - m - logf(ssum);
        __builtin_nontemporal_store(r, out + (size_t)node * NCLASS + lane);
    }
}

// ---------------- launch ----------------

extern "C" void kernel_launch(void* const* d_in, const int* in_sizes, int n_in,
                              void* d_out, int out_size, void* d_ws, size_t ws_size,
                              hipStream_t stream) {
    const float* x  = (const float*)d_in[0];
    const int* row  = (const int*)d_in[1];
    const int* col  = (const int*)d_in[2];
    const float* ew = (const float*)d_in[3];
    const float* W1 = (const float*)d_in[4];
    const float* b1 = (const float*)d_in[5];
    const float* W2 = (const float*)d_in[6];
    const float* b2 = (const float*)d_in[7];
    const float* W3 = (const float*)d_in[8];
    const float* b3 = (const float*)d_in[9];
    const float* W4 = (const float*)d_in[10];
    const float* b4 = (const float*)d_in[11];
    float* out = (float*)d_out;

    const int Nn = in_sizes[0] / NFEAT;
    const int E  = in_sizes[1];
    const int NB = (Nn + 255) / 256;
    const int Mpad = (Nn + 127) & ~127;

    char* ws = (char*)d_ws;
    size_t off = 0;
    auto alloc = [&](size_t bytes) {
        size_t o = off;
        off = (off + bytes + 255) & ~(size_t)255;
        return o;
    };
    int*   row_ptr  = (int*)(ws + alloc((size_t)(Nn + 1) * 4));
    int*   counts   = (int*)(ws + alloc((size_t)Nn * 4));       // also reused as cursor
    int*   partials = (int*)(ws + alloc((size_t)NB * 4));
    uint2* csr_cw   = (uint2*)(ws + alloc((size_t)E * 8));
    unsigned short* Sb  = (unsigned short*)(ws + alloc((size_t)Mpad * NHID * 2));
    unsigned short* Hb  = (unsigned short*)(ws + alloc((size_t)Mpad * NHID * 2));
    unsigned short* S4b = (unsigned short*)(ws + alloc((size_t)Mpad * NCLASS * 2));
    unsigned short* Wt1 = (unsigned short*)(ws + alloc((size_t)128 * 512 * 2));
    unsigned short* Wt2 = (unsigned short*)(ws + alloc((size_t)128 * 128 * 2));
    unsigned short* Wt3 = (unsigned short*)(ws + alloc((size_t)128 * 128 * 2));
    unsigned short* Wt4 = (unsigned short*)(ws + alloc((size_t)48 * 128 * 2));

    // ---- weight prep ----
    k_prep_w<<<(128 * 512 + 255) / 256, 256, 0, stream>>>(W1, Wt1, NFEAT, NHID, 128, 512);
    k_prep_w<<<(128 * 128 + 255) / 256, 256, 0, stream>>>(W2, Wt2, NHID, NHID, 128, 128);
    k_prep_w<<<(128 * 128 + 255) / 256, 256, 0, stream>>>(W3, Wt3, NHID, NHID, 128, 128);
    k_prep_w<<<(48 * 128 + 255) / 256, 256, 0, stream>>>(W4, Wt4, NHID, NCLASS, 48, 128);

    // ---- CSR build ----
    (void)hipMemsetAsync(counts, 0, (size_t)Nn * 4, stream);
    k_hist<<<(E + 255) / 256, 256, 0, stream>>>(row, E, counts);
    k_block_sum<<<NB, 256, 0, stream>>>(counts, Nn, partials);
    k_scan_partials<<<1, 512, 0, stream>>>(partials, NB);
    k_scan_counts<<<NB, 256, 0, stream>>>(counts, partials, row_ptr, Nn);
    k_scatter<<<(E + 255) / 256, 256, 0, stream>>>(row, col, ew, E, row_ptr, counts, csr_cw);

    const int gblocks = Mpad / 128;
    const int spmm_blocks = (Nn + 3) / 4;

    // layer 1: x @ W1 -> Sb ; spmm+b1+relu -> Hb
    k_gemm_lds<true, 512, 128, 128, 128><<<gblocks, 256, 0, stream>>>(x, Wt1, Sb, Nn, NFEAT);
    k_spmm128<<<spmm_blocks, 256, 0, stream>>>(Sb, row_ptr, csr_cw, b1, Hb, Nn, 1);
    // layer 2
    k_gemm_lds<false, 128, 128, 128, 128><<<gblocks, 256, 0, stream>>>(Hb, Wt2, Sb, Nn, NHID);
    k_spmm128<<<spmm_blocks, 256, 0, stream>>>(Sb, row_ptr, csr_cw, b2, Hb, Nn, 1);
    // layer 3
    k_gemm_lds<false, 128, 128, 128, 128><<<gblocks, 256, 0, stream>>>(Hb, Wt3, Sb, Nn, NHID);
    k_spmm128<<<spmm_blocks, 256, 0, stream>>>(Sb, row_ptr, csr_cw, b3, Hb, Nn, 1);
    // layer 4: Hb @ W4 -> S4b[N,40] ; spmm+b4+log_softmax -> out (fp32)
    k_gemm_lds<false, 128, 48, 40, 40><<<gblocks, 256, 0, stream>>>(Hb, Wt4, S4b, Nn, NHID);
    k_spmm40_lsm<<<spmm_blocks, 256, 0, stream>>>(S4b, row_ptr, csr_cw, b4, out, Nn);
}